// Round 1
// baseline (103.091 us; speedup 1.0000x reference)
//
#include <hip/hip_runtime.h>
#include <math.h>

// Problem constants (B=8, P=64, V=32, N_TH1=30 -> D=1626)
#define NBP 512          // B*P
#define VV 32
#define DD 1626
#define CHUNKS 4
#define DPC 407          // ceil(DD/CHUNKS)

// Output layout (flat float32, concatenated in return order)
#define O_POINTS 0                         // (8,64*1626,3)  = 2497536
#define O_DIRH   2497536                   // (8,64,1626,4)  = 3330048
#define O_OVER   5827584                   // (8,64,1)       = 512
#define O_RETR   5828096                   // (8,64,1)       = 512
#define O_MEAN   5828608                   // (8,64,3)       = 1536
#define O_LOCAL  5830144                   // (8,64,32,3)    = 49152
// total = 5879296

__global__ __launch_bounds__(256) void spt_kernel(
    const float* __restrict__ vertices,
    const float* __restrict__ smooth,
    float* __restrict__ out)
{
  const int bp    = blockIdx.x;   // 0..511 : (b*64+p)
  const int chunk = blockIdx.y;   // 0..3   : direction chunk
  const int tid   = threadIdx.x;

  __shared__ float vb[VV * 3];
  __shared__ float lv[VV * 3];
  __shared__ float meanv[3];
  __shared__ float sdir[DPC * 3];

  // ---- stage vertices for this (b,p) ----
  if (tid < VV * 3) vb[tid] = vertices[bp * (VV * 3) + tid];

  // ---- compute this chunk's directions into LDS (fp32 trig; poles hardcoded
  //      to the numpy-f64-then-cast values) ----
  const int dbase = chunk * DPC;
  for (int i = tid; i < DPC; i += 256) {
    int d = dbase + i;
    float x, y, z;
    if (d < 1624) {
      int i1 = d / 58;          // 0..27
      int i2 = d - i1 * 58;     // 0..57
      i1 += 1;                  // th1 index 1..28
      const float STEP = 0.10833078115826873f;   // pi/29
      float th1 = -1.5707963267948966f + (float)i1 * STEP;
      float th2 = -3.14159265358979323846f + (float)i2 * STEP;
      float s1, c1, s2, c2;
      sincosf(th1, &s1, &c1);
      sincosf(th2, &s2, &c2);
      x = c1 * c2; y = c1 * s2; z = s1;
    } else if (d == 1624) {     // pole at th1=-pi/2, th2=-pi
      x = -6.123234e-17f; y = -7.49880e-33f; z = -1.0f;
    } else {                    // d==1625 (or pad): pole at th1=+pi/2
      x = -6.123234e-17f; y = -7.49880e-33f; z = 1.0f;
    }
    sdir[i * 3 + 0] = x;
    sdir[i * 3 + 1] = y;
    sdir[i * 3 + 2] = z;
  }
  __syncthreads();

  // ---- mean over vertices ----
  if (tid < 3) {
    float s = 0.f;
#pragma unroll
    for (int v = 0; v < VV; v++) s += vb[v * 3 + tid];
    meanv[tid] = s * (1.0f / 32.0f);
  }
  __syncthreads();
  if (tid < VV * 3) lv[tid] = vb[tid] - meanv[tid % 3];
  __syncthreads();

  // ---- side outputs (once, by chunk 0) ----
  if (chunk == 0) {
    if (tid < VV * 3) out[O_LOCAL + bp * (VV * 3) + tid] = lv[tid];
    if (tid < 3)      out[O_MEAN + bp * 3 + tid] = meanv[tid];
    if (tid == 3)     out[O_OVER + bp] = 0.f;
    if (tid == 4)     out[O_RETR + bp] = 0.f;
  }

  const float p     = smooth[bp];
  const float inv_p = 1.0f / p;
  const float pm1   = p - 1.0f;
  const float mx = meanv[0], my = meanv[1], mz = meanv[2];

  const int dend = (DD - dbase) < DPC ? (DD - dbase) : DPC;
  for (int i = tid; i < dend; i += 256) {
    const int d = dbase + i;
    const float dx = sdir[i * 3 + 0];
    const float dy = sdir[i * 3 + 1];
    const float dz = sdir[i * 3 + 2];

    // pass 1: z = lv . dir, relu, max over v
    float zm[VV];
    float zmax = 0.f;
#pragma unroll
    for (int v = 0; v < VV; v++) {
      float zv = fmaf(lv[v * 3 + 0], dx,
                  fmaf(lv[v * 3 + 1], dy, lv[v * 3 + 2] * dz));
      zv = fmaxf(zv, 0.f);
      zm[v] = zv;
      zmax = fmaxf(zmax, zv);
    }

    // rescale factor k = 10^clip(ceil(lk),0,20)
    float expo = log10f(zmax) * p;          // -inf if zmax==0
    float kc = 0.f;
    if (expo < -20.f) {
      kc = ceilf((-15.f - expo) * inv_p);   // +inf handled by clamp below
      kc = fminf(fmaxf(kc, 0.f), 20.f);
    }
    const float kk = exp10f(kc);

    // pass 2: zm *= k ; sum of clip(zm^p, 1e-20, 1e20) over positive entries
    float ssum = 0.f;
#pragma unroll
    for (int v = 0; v < VV; v++) {
      float zs = zm[v] * kk;
      zm[v] = zs;
      float zp = 0.f;
      if (zs > 0.f) {
        zp = exp2f(p * __log2f(zs));
        zp = fminf(fmaxf(zp, 1e-20f), 1e20f);
      }
      ssum += zp;
    }

    float h = 1e-20f;
    if (ssum > 0.f) {
      h = exp2f(inv_p * __log2f(ssum));
      h = fminf(fmaxf(h, 1e-20f), 1e20f);
    }
    const float invh = 1.0f / h;

    // pass 3: dhdz = clip((zm/h)^(p-1), 1e-20, 1e20) else 1e-20 ; dhdx
    float ax = 0.f, ay = 0.f, az = 0.f;
#pragma unroll
    for (int v = 0; v < VV; v++) {
      float ratio = zm[v] * invh;
      float dh;
      if (ratio > 0.f) {
        dh = exp2f(pm1 * __log2f(ratio));
        dh = fminf(fmaxf(dh, 1e-20f), 1e20f);
      } else {
        dh = 1e-20f;
      }
      ax = fmaf(dh, lv[v * 3 + 0], ax);
      ay = fmaf(dh, lv[v * 3 + 1], ay);
      az = fmaf(dh, lv[v * 3 + 2], az);
    }

    // outputs
    const int pbase = bp * DD + d;
    out[O_POINTS + pbase * 3 + 0] = ax + mx;
    out[O_POINTS + pbase * 3 + 1] = ay + my;
    out[O_POINTS + pbase * 3 + 2] = az + mz;

    float hout = h / kk;
    hout = fminf(fmaxf(hout, -1e20f), 1e20f);
    out[O_DIRH + pbase * 4 + 0] = dx;
    out[O_DIRH + pbase * 4 + 1] = dy;
    out[O_DIRH + pbase * 4 + 2] = dz;
    out[O_DIRH + pbase * 4 + 3] = hout;
  }
}

extern "C" void kernel_launch(void* const* d_in, const int* in_sizes, int n_in,
                              void* d_out, int out_size, void* d_ws, size_t ws_size,
                              hipStream_t stream) {
  const float* vertices = (const float*)d_in[0];  // (8,64,32,3) f32
  const float* smooth   = (const float*)d_in[1];  // (8,64) f32
  // d_in[2] (pointcloud) is unused by the reference outputs
  float* out = (float*)d_out;

  spt_kernel<<<dim3(NBP, CHUNKS), 256, 0, stream>>>(vertices, smooth, out);
}

// Round 3
// 92.842 us; speedup vs baseline: 1.1104x; 1.1104x over previous
//
#include <hip/hip_runtime.h>
#include <math.h>

// Problem constants (B=8, P=64, V=32, N_TH1=30 -> D=1626)
#define NBP 512          // B*P
#define VV 32
#define DD 1626
#define CHUNKS 4
#define DPC 407          // ceil(DD/CHUNKS)

// Output layout (flat float32, concatenated in return order)
#define O_POINTS 0                         // (8,64*1626,3)  = 2497536
#define O_DIRH   2497536                   // (8,64,1626,4)  = 3330048
#define O_OVER   5827584                   // (8,64,1)       = 512
#define O_RETR   5828096                   // (8,64,1)       = 512
#define O_MEAN   5828608                   // (8,64,3)       = 1536
#define O_LOCAL  5830144                   // (8,64,32,3)    = 49152
// total = 5879296

#define L10_2 0.3010299956639812f    // log10(2)
#define L2_10 3.321928094887362f     // log2(10)
#define LH_MIN -66.43856189774725f   // log2(1e-20)

__device__ __forceinline__ void make_dir(int d, float& x, float& y, float& z) {
  if (d < 1624) {
    int i1 = d / 58;          // 0..27
    int i2 = d - i1 * 58;     // 0..57
    i1 += 1;
    const float STEP = 0.10833078115826873f;   // pi/29
    float th1 = -1.5707963267948966f + (float)i1 * STEP;
    float th2 = -3.14159265358979323846f + (float)i2 * STEP;
    float s1, c1, s2, c2;
    sincosf(th1, &s1, &c1);
    sincosf(th2, &s2, &c2);
    x = c1 * c2; y = c1 * s2; z = s1;
  } else if (d == 1624) {     // pole th1=-pi/2
    x = -6.123234e-17f; y = -7.49880e-33f; z = -1.0f;
  } else {                    // pole th1=+pi/2
    x = -6.123234e-17f; y = -7.49880e-33f; z = 1.0f;
  }
}

__global__ __launch_bounds__(256) void dirs_kernel(float* __restrict__ gdirs) {
  int d = blockIdx.x * 256 + threadIdx.x;
  if (d >= DD) return;
  float x, y, z;
  make_dir(d, x, y, z);
  gdirs[d * 3 + 0] = x;
  gdirs[d * 3 + 1] = y;
  gdirs[d * 3 + 2] = z;
}

__global__ __launch_bounds__(256) void spt_kernel(
    const float* __restrict__ vertices,
    const float* __restrict__ smooth,
    const float* __restrict__ gdirs,   // may be null -> compute in-kernel
    float* __restrict__ out)
{
  const int bp    = blockIdx.x;   // 0..511
  const int chunk = blockIdx.y;   // 0..3
  const int tid   = threadIdx.x;

  __shared__ float vb[VV * 3];
  __shared__ float lv[VV * 3];
  __shared__ float meanv[3];
  __shared__ float sdir[DPC * 3];

  if (tid < VV * 3) vb[tid] = vertices[bp * (VV * 3) + tid];

  const int dbase = chunk * DPC;
  const int dend  = (DD - dbase) < DPC ? (DD - dbase) : DPC;

  if (gdirs) {
    // coalesced stage of this chunk's directions
    for (int i = tid; i < dend * 3; i += 256) sdir[i] = gdirs[dbase * 3 + i];
  } else {
    for (int i = tid; i < dend; i += 256) {
      float x, y, z;
      make_dir(dbase + i, x, y, z);
      sdir[i * 3 + 0] = x; sdir[i * 3 + 1] = y; sdir[i * 3 + 2] = z;
    }
  }
  __syncthreads();

  if (tid < 3) {
    float s = 0.f;
#pragma unroll
    for (int v = 0; v < VV; v++) s += vb[v * 3 + tid];
    meanv[tid] = s * (1.0f / 32.0f);
  }
  __syncthreads();
  if (tid < VV * 3) lv[tid] = vb[tid] - meanv[tid % 3];
  __syncthreads();

  if (chunk == 0) {
    if (tid < VV * 3) out[O_LOCAL + bp * (VV * 3) + tid] = lv[tid];
    if (tid < 3)      out[O_MEAN + bp * 3 + tid] = meanv[tid];
    if (tid == 3)     out[O_OVER + bp] = 0.f;
    if (tid == 4)     out[O_RETR + bp] = 0.f;
  }

  const float p     = smooth[bp];
  const float inv_p = 1.0f / p;
  const float pm1   = p - 1.0f;
  const float mx = meanv[0], my = meanv[1], mz = meanv[2];

  for (int i = tid; i < dend; i += 256) {
    const int d = dbase + i;
    const float dx = sdir[i * 3 + 0];
    const float dy = sdir[i * 3 + 1];
    const float dz = sdir[i * 3 + 2];

    // pass 1: z = lv.dir, relu, max; keep log2 of each (log2(0) = -inf)
    float lz[VV];
    float zmax = 0.f;
#pragma unroll
    for (int v = 0; v < VV; v++) {
      float zv = fmaf(lv[v * 3 + 0], dx,
                  fmaf(lv[v * 3 + 1], dy, lv[v * 3 + 2] * dz));
      zv = fmaxf(zv, 0.f);
      zmax = fmaxf(zmax, zv);
      lz[v] = __log2f(zv);
    }

    // rescale exponent kc = clip(ceil((-15 - p*log10(zmax)) / p), 0, 20) when
    // p*log10(zmax) < -20, else 0.  (zmax==0 -> expo=-inf -> kc=20)
    const float expo = __log2f(zmax) * (p * L10_2);
    float kc = 0.f;
    if (expo < -20.f) {
      kc = fminf(fmaxf(ceilf((-15.f - expo) * inv_p), 0.f), 20.f);
    }
    const float kcl = kc * L2_10;    // log2(k)
    const float pkc = p * kcl;

    // pass 2: ssum = sum min((zm*k)^p, 1e20)   [(zm*k)^p = 2^(p*lz + p*kcl)]
    float ssum = 0.f;
#pragma unroll
    for (int v = 0; v < VV; v++) {
      float zp = exp2f(fmaf(p, lz[v], pkc));
      zp = fminf(zp, 1e20f);
      ssum += zp;
    }

    float lh = LH_MIN;                       // log2(h); h=1e-20 if sum==0
    if (ssum > 0.f) lh = inv_p * __log2f(ssum);

    // pass 3: dhdz = 2^((p-1)*lz + (p-1)*(kcl - lh)) ; dhdx = sum dhdz*lv
    const float c3 = pm1 * (kcl - lh);
    float ax = 0.f, ay = 0.f, az = 0.f;
#pragma unroll
    for (int v = 0; v < VV; v++) {
      float dh = exp2f(fmaf(pm1, lz[v], c3));
      dh = fminf(dh, 1e20f);
      ax = fmaf(dh, lv[v * 3 + 0], ax);
      ay = fmaf(dh, lv[v * 3 + 1], ay);
      az = fmaf(dh, lv[v * 3 + 2], az);
    }

    const int pbase = bp * DD + d;
    out[O_POINTS + pbase * 3 + 0] = ax + mx;
    out[O_POINTS + pbase * 3 + 1] = ay + my;
    out[O_POINTS + pbase * 3 + 2] = az + mz;

    const float hout = exp2f(lh - kcl);    // h / k  (clips inactive)
    out[O_DIRH + pbase * 4 + 0] = dx;
    out[O_DIRH + pbase * 4 + 1] = dy;
    out[O_DIRH + pbase * 4 + 2] = dz;
    out[O_DIRH + pbase * 4 + 3] = hout;
  }
}

extern "C" void kernel_launch(void* const* d_in, const int* in_sizes, int n_in,
                              void* d_out, int out_size, void* d_ws, size_t ws_size,
                              hipStream_t stream) {
  const float* vertices = (const float*)d_in[0];  // (8,64,32,3) f32
  const float* smooth   = (const float*)d_in[1];  // (8,64) f32
  float* out = (float*)d_out;

  const size_t dirs_bytes = (size_t)DD * 3 * sizeof(float);
  float* gdirs = (ws_size >= dirs_bytes) ? (float*)d_ws : nullptr;

  if (gdirs) {
    dirs_kernel<<<dim3((DD + 255) / 256), 256, 0, stream>>>(gdirs);
  }
  spt_kernel<<<dim3(NBP, CHUNKS), 256, 0, stream>>>(vertices, smooth, gdirs, out);
}

// Round 4
// 80.511 us; speedup vs baseline: 1.2804x; 1.1532x over previous
//
#include <hip/hip_runtime.h>
#include <math.h>

// Problem constants (B=8, P=64, V=32, N_TH1=30 -> D=1626)
#define NBP 512          // B*P
#define VV 32
#define DD 1626
#define TILE 256         // directions per block
#define NTILES 7         // ceil(1626/256)

// Output layout (flat float32, concatenated in return order)
#define O_POINTS 0                         // (8,64*1626,3)  = 2497536
#define O_DIRH   2497536                   // (8,64,1626,4)  = 3330048
#define O_OVER   5827584                   // (8,64,1)       = 512
#define O_RETR   5828096                   // (8,64,1)       = 512
#define O_MEAN   5828608                   // (8,64,3)       = 1536
#define O_LOCAL  5830144                   // (8,64,32,3)    = 49152

#define L10_2 0.3010299956639812f    // log10(2)
#define L2_10 3.321928094887362f     // log2(10)
#define LH_MIN -66.43856189774725f   // log2(1e-20)

__device__ __forceinline__ float fexp2(float x) {
  return __builtin_amdgcn_exp2f(x);    // raw v_exp_f32
}

__device__ __forceinline__ void make_dir(int d, float& x, float& y, float& z) {
  if (d < 1624) {
    int i1 = d / 58;
    int i2 = d - i1 * 58;
    i1 += 1;
    const float STEP = 0.10833078115826873f;   // pi/29
    float th1 = -1.5707963267948966f + (float)i1 * STEP;
    float th2 = -3.14159265358979323846f + (float)i2 * STEP;
    float s1, c1, s2, c2;
    sincosf(th1, &s1, &c1);
    sincosf(th2, &s2, &c2);
    x = c1 * c2; y = c1 * s2; z = s1;
  } else if (d == 1624) {
    x = -6.123234e-17f; y = -7.49880e-33f; z = -1.0f;
  } else {
    x = -6.123234e-17f; y = -7.49880e-33f; z = 1.0f;
  }
}

__global__ __launch_bounds__(256) void dirs_kernel(float* __restrict__ gdirs) {
  int d = blockIdx.x * 256 + threadIdx.x;
  if (d >= DD) return;
  float x, y, z;
  make_dir(d, x, y, z);
  gdirs[d * 3 + 0] = x;
  gdirs[d * 3 + 1] = y;
  gdirs[d * 3 + 2] = z;
}

__global__ __launch_bounds__(256) void spt_kernel(
    const float* __restrict__ vertices,
    const float* __restrict__ smooth,
    const float* __restrict__ gdirs,
    float* __restrict__ out)
{
  const int bp    = blockIdx.x;   // 0..511
  const int tile  = blockIdx.y;   // 0..6
  const int tid   = threadIdx.x;

  __shared__ float vb[VV * 3];
  __shared__ __align__(16) float slvx[VV];
  __shared__ __align__(16) float slvy[VV];
  __shared__ __align__(16) float slvz[VV];
  __shared__ float meanv[3];
  __shared__ __align__(16) float4 sdir[TILE];

  if (tid < VV * 3) vb[tid] = vertices[bp * (VV * 3) + tid];

  const int dbase = tile * TILE;
  const int dend  = (DD - dbase) < TILE ? (DD - dbase) : TILE;

  // stage this tile's directions into LDS as float4 (w = pad)
  if (tid < dend) {
    const float* g = gdirs + (size_t)(dbase + tid) * 3;
    sdir[tid] = make_float4(g[0], g[1], g[2], 0.f);
  }
  __syncthreads();

  if (tid < 3) {
    float s = 0.f;
#pragma unroll
    for (int v = 0; v < VV; v++) s += vb[v * 3 + tid];
    meanv[tid] = s * (1.0f / 32.0f);
  }
  __syncthreads();
  if (tid < VV) {
    slvx[tid] = vb[tid * 3 + 0] - meanv[0];
    slvy[tid] = vb[tid * 3 + 1] - meanv[1];
    slvz[tid] = vb[tid * 3 + 2] - meanv[2];
  }
  __syncthreads();

  if (tile == 0) {
    if (tid < VV * 3) out[O_LOCAL + bp * (VV * 3) + tid] = vb[tid] - meanv[tid % 3];
    if (tid < 3)      out[O_MEAN + bp * 3 + tid] = meanv[tid];
    if (tid == 3)     out[O_OVER + bp] = 0.f;
    if (tid == 4)     out[O_RETR + bp] = 0.f;
  }

  if (tid >= dend) return;

  const float p     = smooth[bp];
  const float inv_p = 1.0f / p;
  const float pm1   = p - 1.0f;
  const float mx = meanv[0], my = meanv[1], mz = meanv[2];

  float4 dv = sdir[tid];
  const float dx = dv.x, dy = dv.y, dz = dv.z;
  const int d = dbase + tid;

  const float4* lvx4 = (const float4*)slvx;
  const float4* lvy4 = (const float4*)slvy;
  const float4* lvz4 = (const float4*)slvz;

  // ---- pass 1: lz[v] = log2(relu(lv.dir)) ; lmax = max lz ----
  float lz[VV];
  float lmax = -INFINITY;
#pragma unroll
  for (int j = 0; j < VV / 4; j++) {
    float4 X = lvx4[j], Y = lvy4[j], Z = lvz4[j];
    float z0 = fmaxf(fmaf(X.x, dx, fmaf(Y.x, dy, Z.x * dz)), 0.f);
    float z1 = fmaxf(fmaf(X.y, dx, fmaf(Y.y, dy, Z.y * dz)), 0.f);
    float z2 = fmaxf(fmaf(X.z, dx, fmaf(Y.z, dy, Z.z * dz)), 0.f);
    float z3 = fmaxf(fmaf(X.w, dx, fmaf(Y.w, dy, Z.w * dz)), 0.f);
    float l0 = __log2f(z0), l1 = __log2f(z1);
    float l2 = __log2f(z2), l3 = __log2f(z3);
    lz[j * 4 + 0] = l0; lz[j * 4 + 1] = l1;
    lz[j * 4 + 2] = l2; lz[j * 4 + 3] = l3;
    lmax = fmaxf(lmax, fmaxf(fmaxf(l0, l1), fmaxf(l2, l3)));
  }

  // rescale exponent: kc = clip(ceil((-15 - p*log10(zmax))/p), 0, 20) when
  // p*log10(zmax) < -20, else 0.   (zmax==0 -> lmax=-inf -> kc=20)
  const float expo = lmax * (p * L10_2);
  float kc = 0.f;
  if (expo < -20.f) {
    kc = fminf(fmaxf(ceilf((-15.f - expo) * inv_p), 0.f), 20.f);
  }
  const float kcl = kc * L2_10;    // log2(k)
  const float pkc = p * kcl;

  // ---- pass 2: ssum = sum min((zm*k)^p, 1e20) = sum min(2^(p*lz+p*kcl),1e20)
  float s0 = 0.f, s1 = 0.f, s2 = 0.f, s3 = 0.f;
#pragma unroll
  for (int j = 0; j < VV / 4; j++) {
    s0 += fminf(fexp2(fmaf(p, lz[j * 4 + 0], pkc)), 1e20f);
    s1 += fminf(fexp2(fmaf(p, lz[j * 4 + 1], pkc)), 1e20f);
    s2 += fminf(fexp2(fmaf(p, lz[j * 4 + 2], pkc)), 1e20f);
    s3 += fminf(fexp2(fmaf(p, lz[j * 4 + 3], pkc)), 1e20f);
  }
  const float ssum = (s0 + s1) + (s2 + s3);

  float lh = LH_MIN;
  if (ssum > 0.f) lh = inv_p * __log2f(ssum);

  // ---- pass 3: dhdz = 2^((p-1)*lz + c3) ; dhdx = sum dhdz*lv ----
  const float c3 = pm1 * (kcl - lh);
  float ax = 0.f, ay = 0.f, az = 0.f;
#pragma unroll
  for (int j = 0; j < VV / 4; j++) {
    float4 X = lvx4[j], Y = lvy4[j], Z = lvz4[j];
    float d0 = fminf(fexp2(fmaf(pm1, lz[j * 4 + 0], c3)), 1e20f);
    float d1 = fminf(fexp2(fmaf(pm1, lz[j * 4 + 1], c3)), 1e20f);
    float d2 = fminf(fexp2(fmaf(pm1, lz[j * 4 + 2], c3)), 1e20f);
    float d3 = fminf(fexp2(fmaf(pm1, lz[j * 4 + 3], c3)), 1e20f);
    ax = fmaf(d0, X.x, fmaf(d1, X.y, fmaf(d2, X.z, fmaf(d3, X.w, ax))));
    ay = fmaf(d0, Y.x, fmaf(d1, Y.y, fmaf(d2, Y.z, fmaf(d3, Y.w, ay))));
    az = fmaf(d0, Z.x, fmaf(d1, Z.y, fmaf(d2, Z.z, fmaf(d3, Z.w, az))));
  }

  const int pbase = bp * DD + d;
  out[O_POINTS + pbase * 3 + 0] = ax + mx;
  out[O_POINTS + pbase * 3 + 1] = ay + my;
  out[O_POINTS + pbase * 3 + 2] = az + mz;

  dv.w = fexp2(lh - kcl);                 // h / k
  ((float4*)(out + O_DIRH))[pbase] = dv;
}

extern "C" void kernel_launch(void* const* d_in, const int* in_sizes, int n_in,
                              void* d_out, int out_size, void* d_ws, size_t ws_size,
                              hipStream_t stream) {
  const float* vertices = (const float*)d_in[0];  // (8,64,32,3) f32
  const float* smooth   = (const float*)d_in[1];  // (8,64) f32
  float* out = (float*)d_out;
  float* gdirs = (float*)d_ws;                    // DD*3 floats

  dirs_kernel<<<dim3((DD + 255) / 256), 256, 0, stream>>>(gdirs);
  spt_kernel<<<dim3(NBP, NTILES), 256, 0, stream>>>(vertices, smooth, gdirs, out);
}